// Round 11
// baseline (291.508 us; speedup 1.0000x reference)
//
#include <hip/hip_runtime.h>
#include <hip/hip_bf16.h>
#include <math.h>

#define HIDDEN 2048
#define HARM   64
#define NHEADS 16
#define HDIM   128
#define SEQ    2048
#define BATCH  2
#define ROWS   (BATCH*SEQ)   // 4096
#define RN     (ROWS*HARM)   // 262144 (one K-chunk partial plane)
#define PN     ((size_t)ROWS*HIDDEN)  // 8388608
#define KCH    8             // K-chunks per resonance pass (chunks of 256)

using bf16x8 = __attribute__((ext_vector_type(8))) short;
using f32x16 = __attribute__((ext_vector_type(16))) float;
using u32x2  = __attribute__((ext_vector_type(2))) unsigned;

#if defined(__has_builtin)
#if __has_builtin(__builtin_amdgcn_exp2f)
#define EXP2F(x) __builtin_amdgcn_exp2f(x)
#else
#define EXP2F(x) exp2f(x)
#endif
#else
#define EXP2F(x) exp2f(x)
#endif

// permlane32_swap via the BUILTIN (compiler inserts required hazard waits —
// raw inline asm reads stale VGPRs after v_cvt_pk: R10 post-mortem).
// Semantics: r0 = {a_lo | b_lo}, r1 = {a_hi | b_hi}.
#if defined(__has_builtin) && __has_builtin(__builtin_amdgcn_permlane32_swap)
__device__ inline void plane_swap_u(unsigned& a, unsigned& b) {
  u32x2 r = __builtin_amdgcn_permlane32_swap(a, b, false, false);
  a = r[0]; b = r[1];
}
__device__ inline void plane_swap_f(float& a, float& b) {
  union { float f; unsigned u; } ua, ub;
  ua.f = a; ub.f = b;
  u32x2 r = __builtin_amdgcn_permlane32_swap(ua.u, ub.u, false, false);
  ua.u = r[0]; ub.u = r[1];
  a = ua.f; b = ub.f;
}
#else
// bit-exact emulation of the same semantics
__device__ inline void plane_swap_u(unsigned& a, unsigned& b) {
  const bool hi = (threadIdx.x & 32) != 0;
  unsigned ax = (unsigned)__shfl_xor((int)a, 32);
  unsigned bx = (unsigned)__shfl_xor((int)b, 32);
  unsigned r0 = hi ? bx : a;
  unsigned r1 = hi ? b : ax;
  a = r0; b = r1;
}
__device__ inline void plane_swap_f(float& a, float& b) {
  const bool hi = (threadIdx.x & 32) != 0;
  float ax = __shfl_xor(a, 32);
  float bx = __shfl_xor(b, 32);
  float r0 = hi ? bx : a;
  float r1 = hi ? b : ax;
  a = r0; b = r1;
}
#endif

// hi/lo double-bf16 split: a ~= hi + lo with ~16-bit effective mantissa
__device__ inline void split_bf(float a, ushort& hi, ushort& lo) {
  __hip_bfloat16 h = __float2bfloat16(a);
  float hf = __bfloat162float(h);
  __hip_bfloat16 l = __float2bfloat16(a - hf);
  union { __hip_bfloat16 b; ushort u; } c1, c2;
  c1.b = h; c2.b = l;
  hi = c1.u; lo = c2.u;
}

// ---------------- fused prep: cast X (blocks 0..8191), w=amp*cos(phase) hi/lo
// (blocks 8192..10239), cast basis q/k/v/o hi/lo (blocks 10240..10751)
__global__ __launch_bounds__(256) void prep(
    const float* __restrict__ X,
    const float* __restrict__ pq, const float* __restrict__ aq,
    const float* __restrict__ pk, const float* __restrict__ ak,
    const float* __restrict__ pv, const float* __restrict__ av,
    const float* __restrict__ po, const float* __restrict__ ao,
    const float* __restrict__ bq, const float* __restrict__ bk,
    const float* __restrict__ bv, const float* __restrict__ bo,
    ushort* __restrict__ Xh, ushort* __restrict__ Xl,
    ushort* __restrict__ Wh, ushort* __restrict__ Wl,
    ushort* __restrict__ Bh, ushort* __restrict__ Bl) {
  const int bid = blockIdx.x;
  const int t = threadIdx.x;
  if (bid < 8192) {
    size_t i = ((size_t)bid * 256 + t) * 4;
    float4 v = *(const float4*)&X[i];
    ushort4 h, l;
    split_bf(v.x, h.x, l.x); split_bf(v.y, h.y, l.y);
    split_bf(v.z, h.z, l.z); split_bf(v.w, h.w, l.w);
    *(ushort4*)&Xh[i] = h;
    *(ushort4*)&Xl[i] = l;
  } else if (bid < 10240) {
    int i = (bid - 8192) * 256 + t;
    const int N = HIDDEN * HARM;
    int set = i / N, j = i - set * N;
    const float* p = (set == 0) ? pq : (set == 1) ? pk : (set == 2) ? pv : po;
    const float* a = (set == 0) ? aq : (set == 1) ? ak : (set == 2) ? av : ao;
    float wv = a[j] * cosf(p[j]);
    ushort h, l;
    split_bf(wv, h, l);
    size_t o = (size_t)set * N + j;
    Wh[o] = h; Wl[o] = l;
  } else {
    int idx = bid - 10240;          // 512 blocks = 128 x 4
    int z = idx >> 7, xb = idx & 127;
    const float* S = (z == 0) ? bq : (z == 1) ? bk : (z == 2) ? bv : bo;
    size_t i = ((size_t)xb * 256 + t) * 4;
    float4 v = *(const float4*)&S[i];
    ushort4 h, l;
    split_bf(v.x, h.x, l.x); split_bf(v.y, h.y, l.y);
    split_bf(v.z, h.z, l.z); split_bf(v.w, h.w, l.w);
    size_t o = (size_t)z * HARM * HIDDEN + i;
    *(ushort4*)&Bh[o] = h;
    *(ushort4*)&Bl[o] = l;
  }
}

// --------------- MFMA resonance (double-bf16): Rp[kc][M][64] = X * basis^T
// 64-row tile / 36.8KB LDS (verified-best geometry). kc=8 chunks of K=256:
// QKV grid 64x8x3=1536 blocks (4/CU, LDS cap) and AO grid 64x8=512 (2/CU) —
// fixes the grid-limited occupancy (AO pass was 256 blocks = 1 wave/SIMD).
__global__ __launch_bounds__(256) void gemm_res(
    const ushort* __restrict__ Xh, const ushort* __restrict__ Xl,
    const ushort* __restrict__ Bh, const ushort* __restrict__ Bl,
    float* __restrict__ R0, float* __restrict__ R1, float* __restrict__ R2) {
  const int z = blockIdx.z;
  const ushort* Bhz = Bh + (size_t)z * HARM * HIDDEN;
  const ushort* Blz = Bl + (size_t)z * HARM * HIDDEN;
  float* Rp = (z == 0) ? R0 : (z == 1) ? R1 : R2;
  const int row0 = blockIdx.x * 64;
  const int kc = blockIdx.y;            // 0..KCH-1
  __shared__ __align__(16) ushort Xs[2][64][72];
  __shared__ __align__(16) ushort Bs[2][64][72];
  const int t = threadIdx.x;
  const int lane = t & 63, w = t >> 6;
  const int l31 = lane & 31, hh = lane >> 5;
  const int m0 = (w & 1) * 32, n0 = (w >> 1) * 32;
  const int srow = t >> 2;
  const int sc = (t & 3) * 16;
  f32x16 acc;
  #pragma unroll
  for (int j = 0; j < 16; ++j) acc[j] = 0.0f;

  const int kbase = kc * (HIDDEN / KCH);           // chunks of 256
  for (int k0 = kbase; k0 < kbase + (HIDDEN / KCH); k0 += 64) {
    const size_t xo = (size_t)(row0 + srow) * HIDDEN + k0 + sc;
    const size_t bo = (size_t)srow * HIDDEN + k0 + sc;
    *(uint4*)&Xs[0][srow][sc]     = *(const uint4*)&Xh[xo];
    *(uint4*)&Xs[0][srow][sc + 8] = *(const uint4*)&Xh[xo + 8];
    *(uint4*)&Xs[1][srow][sc]     = *(const uint4*)&Xl[xo];
    *(uint4*)&Xs[1][srow][sc + 8] = *(const uint4*)&Xl[xo + 8];
    *(uint4*)&Bs[0][srow][sc]     = *(const uint4*)&Bhz[bo];
    *(uint4*)&Bs[0][srow][sc + 8] = *(const uint4*)&Bhz[bo + 8];
    *(uint4*)&Bs[1][srow][sc]     = *(const uint4*)&Blz[bo];
    *(uint4*)&Bs[1][srow][sc + 8] = *(const uint4*)&Blz[bo + 8];
    __syncthreads();
    #pragma unroll
    for (int ks = 0; ks < 4; ++ks) {
      bf16x8 ah = *(const bf16x8*)&Xs[0][m0 + l31][ks * 16 + 8 * hh];
      bf16x8 al = *(const bf16x8*)&Xs[1][m0 + l31][ks * 16 + 8 * hh];
      bf16x8 bh = *(const bf16x8*)&Bs[0][n0 + l31][ks * 16 + 8 * hh];
      bf16x8 bl = *(const bf16x8*)&Bs[1][n0 + l31][ks * 16 + 8 * hh];
      acc = __builtin_amdgcn_mfma_f32_32x32x16_bf16(ah, bh, acc, 0, 0, 0);
      acc = __builtin_amdgcn_mfma_f32_32x32x16_bf16(al, bh, acc, 0, 0, 0);
      acc = __builtin_amdgcn_mfma_f32_32x32x16_bf16(ah, bl, acc, 0, 0, 0);
    }
    __syncthreads();
  }
  float* out = Rp + (size_t)kc * RN;
  #pragma unroll
  for (int r = 0; r < 16; ++r) {
    int mloc = (r & 3) + 8 * (r >> 2) + 4 * hh;
    out[(size_t)(row0 + m0 + mloc) * HARM + n0 + l31] = acc[r];
  }
}

// --------------- MFMA projection (double-bf16): P = (sum_kc Rp) * W^T, bf16 out
// z=0 -> Qb, z=1 -> Kb, z=2 -> V written DIRECTLY TRANSPOSED into VtB via an LDS
// column tile. R staging sums KCH=8 partial planes (left-assoc float4 loads;
// fp32 reorder ~1e-7 << bf16 floor — 8-plane sums verified passing in R16).
__global__ __launch_bounds__(256) void gemm_proj(
    const float* __restrict__ Rp0, const float* __restrict__ Rp1,
    const float* __restrict__ Rp2,
    const ushort* __restrict__ Wh, const ushort* __restrict__ Wl,
    ushort* __restrict__ P0, ushort* __restrict__ P1, ushort* __restrict__ Vt) {
  const int z = blockIdx.z;
  const float* Rp = (z == 0) ? Rp0 : (z == 1) ? Rp1 : Rp2;
  const ushort* Whz = Wh + (size_t)z * HIDDEN * HARM;
  const ushort* Wlz = Wl + (size_t)z * HIDDEN * HARM;
  const int row0 = blockIdx.x * 32;
  const int col0 = blockIdx.y * 128;
  __shared__ __align__(16) union PSM {
    struct { ushort Rs[2][32][72]; ushort Ws[2][128][72]; } s;
    ushort ct[128][36];   // [local col][local row] for the V-transpose epilogue
  } sm;
  const int t = threadIdx.x;
  const int lane = t & 63, w = t >> 6;
  const int l31 = lane & 31, hh = lane >> 5;
  {
    const int r = t >> 3, h0 = (t & 7) * 8;
    const size_t o = (size_t)(row0 + r) * HARM + h0;
    #pragma unroll
    for (int g = 0; g < 2; ++g) {
      const size_t o4 = o + g * 4;
      float4 s = *(const float4*)&Rp[o4];
      #pragma unroll
      for (int pp = 1; pp < KCH; ++pp) {
        float4 q = *(const float4*)&Rp[(size_t)pp * RN + o4];
        s.x += q.x; s.y += q.y; s.z += q.z; s.w += q.w;
      }
      ushort hi, lo;
      split_bf(s.x, hi, lo);
      sm.s.Rs[0][r][h0 + g * 4 + 0] = hi; sm.s.Rs[1][r][h0 + g * 4 + 0] = lo;
      split_bf(s.y, hi, lo);
      sm.s.Rs[0][r][h0 + g * 4 + 1] = hi; sm.s.Rs[1][r][h0 + g * 4 + 1] = lo;
      split_bf(s.z, hi, lo);
      sm.s.Rs[0][r][h0 + g * 4 + 2] = hi; sm.s.Rs[1][r][h0 + g * 4 + 2] = lo;
      split_bf(s.w, hi, lo);
      sm.s.Rs[0][r][h0 + g * 4 + 3] = hi; sm.s.Rs[1][r][h0 + g * 4 + 3] = lo;
    }
  }
  #pragma unroll
  for (int i = 0; i < 4; ++i) {
    int idx = t + i * 256;
    int o = idx >> 3, c8 = (idx & 7) * 8;
    const size_t go = (size_t)(col0 + o) * HARM + c8;
    *(uint4*)&sm.s.Ws[0][o][c8] = *(const uint4*)&Whz[go];
    *(uint4*)&sm.s.Ws[1][o][c8] = *(const uint4*)&Wlz[go];
  }
  __syncthreads();
  const int n0 = w * 32;
  f32x16 acc;
  #pragma unroll
  for (int j = 0; j < 16; ++j) acc[j] = 0.0f;
  #pragma unroll
  for (int ks = 0; ks < 4; ++ks) {
    bf16x8 ah = *(const bf16x8*)&sm.s.Rs[0][l31][ks * 16 + 8 * hh];
    bf16x8 al = *(const bf16x8*)&sm.s.Rs[1][l31][ks * 16 + 8 * hh];
    bf16x8 bh = *(const bf16x8*)&sm.s.Ws[0][n0 + l31][ks * 16 + 8 * hh];
    bf16x8 bl = *(const bf16x8*)&sm.s.Ws[1][n0 + l31][ks * 16 + 8 * hh];
    acc = __builtin_amdgcn_mfma_f32_32x32x16_bf16(ah, bh, acc, 0, 0, 0);
    acc = __builtin_amdgcn_mfma_f32_32x32x16_bf16(al, bh, acc, 0, 0, 0);
    acc = __builtin_amdgcn_mfma_f32_32x32x16_bf16(ah, bl, acc, 0, 0, 0);
  }
  if (z < 2) {
    ushort* P = (z == 0) ? P0 : P1;
    #pragma unroll
    for (int r = 0; r < 16; ++r) {
      int mloc = (r & 3) + 8 * (r >> 2) + 4 * hh;
      union { __hip_bfloat16 b; ushort u; } cv;
      cv.b = __float2bfloat16(acc[r]);
      P[(size_t)(row0 + mloc) * HIDDEN + col0 + n0 + l31] = cv.u;
    }
  } else {
    // V: route through LDS [col][row], store transposed with full 64B lines
    __syncthreads();   // staging reads finished everywhere before aliasing
    #pragma unroll
    for (int r = 0; r < 16; ++r) {
      int mloc = (r & 3) + 8 * (r >> 2) + 4 * hh;
      union { __hip_bfloat16 b; ushort u; } cv;
      cv.b = __float2bfloat16(acc[r]);
      sm.ct[n0 + l31][mloc] = cv.u;
    }
    __syncthreads();
    if (t < 128) {
      const int batch = row0 >> 11;
      const int tok0 = row0 & 2047;
      ushort* dst = Vt + (size_t)batch * SEQ * HIDDEN +
                    (size_t)(col0 + t) * SEQ + tok0;
      #pragma unroll
      for (int j = 0; j < 4; ++j)
        *(uint4*)&dst[j * 8] = *(const uint4*)&sm.ct[t][j * 8];
    }
  }
}

// --------------- MFMA final projection (double-bf16, fp32 out), grid (128, 16)
__global__ __launch_bounds__(256) void gemm_proj_f32(
    const float* __restrict__ Rp,
    const ushort* __restrict__ Whz, const ushort* __restrict__ Wlz,
    float* __restrict__ P) {
  const int row0 = blockIdx.x * 32;
  const int col0 = blockIdx.y * 128;
  __shared__ __align__(16) ushort Rs[2][32][72];
  __shared__ __align__(16) ushort Ws[2][128][72];
  const int t = threadIdx.x;
  const int lane = t & 63, w = t >> 6;
  const int l31 = lane & 31, hh = lane >> 5;
  {
    const int r = t >> 3, h0 = (t & 7) * 8;
    const size_t o = (size_t)(row0 + r) * HARM + h0;
    #pragma unroll
    for (int g = 0; g < 2; ++g) {
      const size_t o4 = o + g * 4;
      float4 s = *(const float4*)&Rp[o4];
      #pragma unroll
      for (int pp = 1; pp < KCH; ++pp) {
        float4 q = *(const float4*)&Rp[(size_t)pp * RN + o4];
        s.x += q.x; s.y += q.y; s.z += q.z; s.w += q.w;
      }
      ushort hi, lo;
      split_bf(s.x, hi, lo);
      Rs[0][r][h0 + g * 4 + 0] = hi; Rs[1][r][h0 + g * 4 + 0] = lo;
      split_bf(s.y, hi, lo);
      Rs[0][r][h0 + g * 4 + 1] = hi; Rs[1][r][h0 + g * 4 + 1] = lo;
      split_bf(s.z, hi, lo);
      Rs[0][r][h0 + g * 4 + 2] = hi; Rs[1][r][h0 + g * 4 + 2] = lo;
      split_bf(s.w, hi, lo);
      Rs[0][r][h0 + g * 4 + 3] = hi; Rs[1][r][h0 + g * 4 + 3] = lo;
    }
  }
  #pragma unroll
  for (int i = 0; i < 4; ++i) {
    int idx = t + i * 256;
    int o = idx >> 3, c8 = (idx & 7) * 8;
    const size_t go = (size_t)(col0 + o) * HARM + c8;
    *(uint4*)&Ws[0][o][c8] = *(const uint4*)&Whz[go];
    *(uint4*)&Ws[1][o][c8] = *(const uint4*)&Wlz[go];
  }
  __syncthreads();
  const int n0 = w * 32;
  f32x16 acc;
  #pragma unroll
  for (int j = 0; j < 16; ++j) acc[j] = 0.0f;
  #pragma unroll
  for (int ks = 0; ks < 4; ++ks) {
    bf16x8 ah = *(const bf16x8*)&Rs[0][l31][ks * 16 + 8 * hh];
    bf16x8 al = *(const bf16x8*)&Rs[1][l31][ks * 16 + 8 * hh];
    bf16x8 bh = *(const bf16x8*)&Ws[0][n0 + l31][ks * 16 + 8 * hh];
    bf16x8 bl = *(const bf16x8*)&Ws[1][n0 + l31][ks * 16 + 8 * hh];
    acc = __builtin_amdgcn_mfma_f32_32x32x16_bf16(ah, bh, acc, 0, 0, 0);
    acc = __builtin_amdgcn_mfma_f32_32x32x16_bf16(al, bh, acc, 0, 0, 0);
    acc = __builtin_amdgcn_mfma_f32_32x32x16_bf16(ah, bl, acc, 0, 0, 0);
  }
  #pragma unroll
  for (int r = 0; r < 16; ++r) {
    int mloc = (r & 3) + 8 * (r >> 2) + 4 * hh;
    P[(size_t)(row0 + mloc) * HIDDEN + col0 + n0 + l31] = acc[r];
  }
}

// ----------------------------------------------------------- MFMA flash attention
// R14 attn verbatim (best verified: ~103-106us, VGPR 88, no spill).
// Double-buffered kv[2] is load-bearing for register lifetime: single-buffer
// keeps kp/vp live across the whole body -> scratch spill (R12/R13).
#define BQ 128
#define BK 64
#define KSTR 136
#define VSTR 72

__device__ inline unsigned pkbf(float a, float b) {
  __hip_bfloat162 h2 = __float22bfloat162_rn(make_float2(a, b));
  union { __hip_bfloat162 h; unsigned u; } cv; cv.h = h2; return cv.u;
}

__global__ __launch_bounds__(256, 2) void attn_mfma(
    const ushort* __restrict__ Qg, const ushort* __restrict__ Kg,
    const ushort* __restrict__ Vt, ushort* __restrict__ Oh,
    ushort* __restrict__ Ol) {
  __shared__ __align__(16) union SM {
    ushort q[BQ][KSTR];
    struct { ushort k[BK][KSTR]; ushort v[HDIM][VSTR]; } kv[2];
  } sm;
  const int t = threadIdx.x;
  const int bh = blockIdx.x & 31;
  const int qt = blockIdx.x >> 5;
  const int b = bh >> 4, h = bh & 15;
  const int q0 = qt * BQ;
  const int lane = t & 63;
  const int w = t >> 6;
  const int l31 = lane & 31;
  const int hh = lane >> 5;
  const float SC2 = 0.08838834764831845f * 1.4426950408889634f;

  const int sk_key = t >> 4;
  const int sk_d0 = (t & 15) * 8;
  const int sv_d = t >> 3;
  const int sv_k = (t & 7) * 8;
  const size_t kbase = ((size_t)(b * SEQ)) * HIDDEN + h * HDIM;
  const size_t vbase = ((size_t)(b * SEQ + h * HDIM)) * SEQ;

  {
    const size_t gbase = ((size_t)(b * SEQ + q0)) * HIDDEN + h * HDIM;
    for (int p = 0; p < 8; ++p) {
      int row = p * 16 + sk_key;
      uint4 v = *(const uint4*)&Qg[gbase + (size_t)row * HIDDEN + sk_d0];
      *(uint4*)&sm.q[row][sk_d0] = v;
    }
  }
  __syncthreads();
  bf16x8 Qf[8];
  {
    const int qrow = w * 32 + l31;
    #pragma unroll
    for (int ks = 0; ks < 8; ++ks)
      Qf[ks] = *(const bf16x8*)&sm.q[qrow][ks * 16 + 8 * hh];
  }
  __syncthreads();

  float mrow = -1e30f, lsum = 0.0f;   // lsum: per-half partial, combined at end
  f32x16 Ot[4];
  #pragma unroll
  for (int i = 0; i < 4; ++i)
    #pragma unroll
    for (int j = 0; j < 16; ++j) Ot[i][j] = 0.0f;
  f32x16 Zv;
  #pragma unroll
  for (int j = 0; j < 16; ++j) Zv[j] = 0.0f;

  uint4 kp[4], vp[4];
  {
    const size_t gb = kbase;
    #pragma unroll
    for (int p = 0; p < 4; ++p)
      kp[p] = *(const uint4*)&Kg[gb + (size_t)(p * 16 + sk_key) * HIDDEN + sk_d0];
    #pragma unroll
    for (int p = 0; p < 4; ++p)
      vp[p] = *(const uint4*)&Vt[vbase + (size_t)(p * 32 + sv_d) * SEQ + sv_k];
    #pragma unroll
    for (int p = 0; p < 4; ++p)
      *(uint4*)&sm.kv[0].k[p * 16 + sk_key][sk_d0] = kp[p];
    #pragma unroll
    for (int p = 0; p < 4; ++p)
      *(uint4*)&sm.kv[0].v[p * 32 + sv_d][sv_k] = vp[p];
  }
  __syncthreads();

  for (int ci = 0; ci < 32; ++ci) {
    {
      const int cn = (ci < 31) ? ci + 1 : 31;
      const size_t gb = kbase + (size_t)(cn * BK) * HIDDEN;
      #pragma unroll
      for (int p = 0; p < 4; ++p)
        kp[p] = *(const uint4*)&Kg[gb + (size_t)(p * 16 + sk_key) * HIDDEN + sk_d0];
      const size_t vb = vbase + cn * BK;
      #pragma unroll
      for (int p = 0; p < 4; ++p)
        vp[p] = *(const uint4*)&Vt[vb + (size_t)(p * 32 + sv_d) * SEQ + sv_k];
    }
    const int cb = ci & 1;

    // ---- QK^T: first MFMA peeled onto a hoisted zero accumulator
    f32x16 C0, C1;
    {
      bf16x8 a0 = *(const bf16x8*)&sm.kv[cb].k[l31][8 * hh];
      bf16x8 a1 = *(const bf16x8*)&sm.kv[cb].k[32 + l31][8 * hh];
      __builtin_amdgcn_s_setprio(1);
      C0 = __builtin_amdgcn_mfma_f32_32x32x16_bf16(a0, Qf[0], Zv, 0, 0, 0);
      C1 = __builtin_amdgcn_mfma_f32_32x32x16_bf16(a1, Qf[0], Zv, 0, 0, 0);
      #pragma unroll
      for (int ks = 1; ks < 8; ++ks) {
        bf16x8 b0 = *(const bf16x8*)&sm.kv[cb].k[l31][ks * 16 + 8 * hh];
        bf16x8 b1 = *(const bf16x8*)&sm.kv[cb].k[32 + l31][ks * 16 + 8 * hh];
        C0 = __builtin_amdgcn_mfma_f32_32x32x16_bf16(b0, Qf[ks], C0, 0, 0, 0);
        C1 = __builtin_amdgcn_mfma_f32_32x32x16_bf16(b1, Qf[ks], C1, 0, 0, 0);
      }
      __builtin_amdgcn_s_setprio(0);
    }

    // ---- row max: ternary tree (fuses to v_max3), then orientation-safe
    // cross-half combine via permlane swap (max of {own, partner})
    float m01[16];
    #pragma unroll
    for (int j = 0; j < 16; ++j) m01[j] = fmaxf(C0[j], C1[j]);
    float x0 = fmaxf(fmaxf(m01[0], m01[1]), m01[2]);
    float x1 = fmaxf(fmaxf(m01[3], m01[4]), m01[5]);
    float x2 = fmaxf(fmaxf(m01[6], m01[7]), m01[8]);
    float x3 = fmaxf(fmaxf(m01[9], m01[10]), m01[11]);
    float x4 = fmaxf(fmaxf(m01[12], m01[13]), m01[14]);
    float mxr = fmaxf(fmaxf(fmaxf(x0, x1), fmaxf(x2, x3)), fmaxf(x4, m01[15]));
    {
      float u = mxr, v2 = mxr;
      plane_swap_f(u, v2);            // -> {lo-bcast, hi-bcast}: fmax = pair max
      mxr = fmaxf(u, v2);
    }

    // ---- exact online max: when no lane grows, every alpha would be exactly
    // 1.0, so skipping the rescale is bit-identical. Inside the branch each
    // lane keeps its own exact mnew (no stale shift -> P stays <= 1).
    const float mg = mxr * SC2;
    if (__any(mg > mrow)) {
      const float mnew = fmaxf(mrow, mg);
      const float alpha = EXP2F(mrow - mnew);   // exactly 1.0 where mg<=mrow
      lsum *= alpha;
      #pragma unroll
      for (int i = 0; i < 4; ++i)
        #pragma unroll
        for (int j = 0; j < 16; ++j) Ot[i][j] *= alpha;
      mrow = mnew;
    }
    float s0 = 0.0f, s1 = 0.0f, s2 = 0.0f, s3 = 0.0f;
    #pragma unroll
    for (int j = 0; j < 16; ++j) {
      float e0 = EXP2F(fmaf(C0[j], SC2, -mrow));
      float e1 = EXP2F(fmaf(C1[j], SC2, -mrow));
      C0[j] = e0; C1[j] = e1;
      if (j & 1) { s2 += e0; s3 += e1; } else { s0 += e0; s1 += e1; }
    }
    lsum += (s0 + s1) + (s2 + s3);   // per-half partial; combined in epilogue

    // ---- PV: packed pairs + permlane32_swap operand build (T12 recipe).
    #pragma unroll
    for (int st = 0; st < 4; ++st) {
      const int eb = 8 * (st & 1);
      unsigned A0, A1, B0, B1;
      if (st < 2) {
        A0 = pkbf(C0[eb + 0], C0[eb + 1]); A1 = pkbf(C0[eb + 2], C0[eb + 3]);
        B0 = pkbf(C0[eb + 4], C0[eb + 5]); B1 = pkbf(C0[eb + 6], C0[eb + 7]);
      } else {
        A0 = pkbf(C1[eb + 0], C1[eb + 1]); A1 = pkbf(C1[eb + 2], C1[eb + 3]);
        B0 = pkbf(C1[eb + 4], C1[eb + 5]); B1 = pkbf(C1[eb + 6], C1[eb + 7]);
      }
      plane_swap_u(A0, B0);
      plane_swap_u(A1, B1);
      union { unsigned u[4]; bf16x8 v; } cv;
      cv.u[0] = A0; cv.u[1] = A1; cv.u[2] = B0; cv.u[3] = B1;
      __builtin_amdgcn_s_setprio(1);
      #pragma unroll
      for (int mt = 0; mt < 4; ++mt) {
        bf16x8 a2 = *(const bf16x8*)&sm.kv[cb].v[mt * 32 + l31][st * 16 + 8 * hh];
        Ot[mt] = __builtin_amdgcn_mfma_f32_32x32x16_bf16(a2, cv.v, Ot[mt], 0, 0, 0);
      }
      __builtin_amdgcn_s_setprio(0);
    }

    {
      const int nb = cb ^ 1;
      #pragma unroll
      for (int p = 0; p < 4; ++p)
        *(uint4*)&sm.kv[nb].k[p * 16 + sk_key][sk_d0] = kp[p];
      #pragma unroll
      for (int p = 0; p < 4; ++p)
        *(uint4*)&sm.kv[nb].v[p * 32 + sv_d][sv_k] = vp[p];
    }
    __syncthreads();
  }

  // ---- epilogue: combine per-half lsum (orientation-safe swap-sum), then
  // normalized AO as bf16 hi/lo planes
  {
    float u = lsum, v2 = lsum;
    plane_swap_f(u, v2);
    lsum = u + v2;
  }
  const float inv = 1.0f / lsum;
  const int qrow = q0 + w * 32 + l31;
  const size_t ob = ((size_t)(b * SEQ + qrow)) * HIDDEN + h * HDIM;
  #pragma unroll
  for (int mt = 0; mt < 4; ++mt)
    #pragma unroll
    for (int g = 0; g < 4; ++g) {
      ushort4 hs, ls;
      split_bf(Ot[mt][4 * g + 0] * inv, hs.x, ls.x);
      split_bf(Ot[mt][4 * g + 1] * inv, hs.y, ls.y);
      split_bf(Ot[mt][4 * g + 2] * inv, hs.z, ls.z);
      split_bf(Ot[mt][4 * g + 3] * inv, hs.w, ls.w);
      const size_t off = ob + mt * 32 + 8 * g + 4 * hh;
      *(ushort4*)&Oh[off] = hs;
      *(ushort4*)&Ol[off] = ls;
    }
}

// -------------------------------------------------------------------------- launcher
extern "C" void kernel_launch(void* const* d_in, const int* in_sizes, int n_in,
                              void* d_out, int out_size, void* d_ws, size_t ws_size,
                              hipStream_t stream) {
  (void)in_sizes; (void)n_in; (void)out_size; (void)ws_size;
  const float* X       = (const float*)d_in[0];
  const float* basis_q = (const float*)d_in[1];
  const float* phase_q = (const float*)d_in[2];
  const float* amp_q   = (const float*)d_in[3];
  const float* basis_k = (const float*)d_in[4];
  const float* phase_k = (const float*)d_in[5];
  const float* amp_k   = (const float*)d_in[6];
  const float* basis_v = (const float*)d_in[7];
  const float* phase_v = (const float*)d_in[8];
  const float* amp_v   = (const float*)d_in[9];
  const float* basis_o = (const float*)d_in[10];
  const float* phase_o = (const float*)d_in[11];
  const float* amp_o   = (const float*)d_in[12];

  const size_t WN = (size_t)HIDDEN * HARM;   // 131072

  char* p = (char*)d_ws;
  ushort* Xhi = (ushort*)p; p += PN * 2;
  ushort* Xlo = (ushort*)p; p += PN * 2;
  ushort* Bhi = (ushort*)p; p += 4 * WN * 2;
  ushort* Blo = (ushort*)p; p += 4 * WN * 2;
  ushort* Whi = (ushort*)p; p += 4 * WN * 2;
  ushort* Wlo = (ushort*)p; p += 4 * WN * 2;
  float* Rqp = (float*)p; p += (size_t)KCH * RN * 4;
  float* Rkp = (float*)p; p += (size_t)KCH * RN * 4;
  float* Rvp = (float*)p; p += (size_t)KCH * RN * 4;
  float* Rop = (float*)p; p += (size_t)KCH * RN * 4;
  __hip_bfloat16* Qb = (__hip_bfloat16*)p; p += PN * 2;
  __hip_bfloat16* Kb = (__hip_bfloat16*)p; p += PN * 2;
  __hip_bfloat16* VtB = (__hip_bfloat16*)p; p += PN * 2;
  ushort* AOh = (ushort*)p; p += PN * 2;
  ushort* AOl = (ushort*)p; p += PN * 2;
  float* out = (float*)d_out;

  prep<<<10752, 256, 0, stream>>>(X,
                                  phase_q, amp_q, phase_k, amp_k,
                                  phase_v, amp_v, phase_o, amp_o,
                                  basis_q, basis_k, basis_v, basis_o,
                                  Xhi, Xlo, Whi, Wlo, Bhi, Blo);

  gemm_res<<<dim3(64, KCH, 3), 256, 0, stream>>>(
      Xhi, Xlo, Bhi, Blo, Rqp, Rkp, Rvp);

  gemm_proj<<<dim3(128, 16, 3), 256, 0, stream>>>(
      Rqp, Rkp, Rvp, Whi, Wlo, (ushort*)Qb, (ushort*)Kb, (ushort*)VtB);

  attn_mfma<<<dim3((SEQ / BQ) * 32), 256, 0, stream>>>(
      (const ushort*)Qb, (const ushort*)Kb, (const ushort*)VtB, AOh, AOl);

  gemm_res<<<dim3(64, KCH, 1), 256, 0, stream>>>(
      AOh, AOl, Bhi + 3 * WN, Blo + 3 * WN, Rop, Rop, Rop);

  gemm_proj_f32<<<dim3(128, 16), 256, 0, stream>>>(
      Rop, Whi + 3 * WN, Wlo + 3 * WN, out);
}

// Round 12
// 256.892 us; speedup vs baseline: 1.1347x; 1.1347x over previous
//
#include <hip/hip_runtime.h>
#include <hip/hip_bf16.h>
#include <math.h>

#define HIDDEN 2048
#define HARM   64
#define NHEADS 16
#define HDIM   128
#define SEQ    2048
#define BATCH  2
#define ROWS   (BATCH*SEQ)   // 4096
#define RN     (ROWS*HARM)   // 262144 (one K-chunk partial plane)
#define PN     ((size_t)ROWS*HIDDEN)  // 8388608

using bf16x8 = __attribute__((ext_vector_type(8))) short;
using f32x16 = __attribute__((ext_vector_type(16))) float;
using u32x2  = __attribute__((ext_vector_type(2))) unsigned;

#if defined(__has_builtin)
#if __has_builtin(__builtin_amdgcn_exp2f)
#define EXP2F(x) __builtin_amdgcn_exp2f(x)
#else
#define EXP2F(x) exp2f(x)
#endif
#else
#define EXP2F(x) exp2f(x)
#endif

// permlane32_swap via the BUILTIN (compiler inserts required hazard waits —
// raw inline asm reads stale VGPRs after v_cvt_pk: R10 post-mortem).
// Semantics: r0 = {a_lo | b_lo}, r1 = {a_hi | b_hi}.
#if defined(__has_builtin) && __has_builtin(__builtin_amdgcn_permlane32_swap)
__device__ inline void plane_swap_u(unsigned& a, unsigned& b) {
  u32x2 r = __builtin_amdgcn_permlane32_swap(a, b, false, false);
  a = r[0]; b = r[1];
}
__device__ inline void plane_swap_f(float& a, float& b) {
  union { float f; unsigned u; } ua, ub;
  ua.f = a; ub.f = b;
  u32x2 r = __builtin_amdgcn_permlane32_swap(ua.u, ub.u, false, false);
  ua.u = r[0]; ub.u = r[1];
  a = ua.f; b = ub.f;
}
#else
// bit-exact emulation of the same semantics
__device__ inline void plane_swap_u(unsigned& a, unsigned& b) {
  const bool hi = (threadIdx.x & 32) != 0;
  unsigned ax = (unsigned)__shfl_xor((int)a, 32);
  unsigned bx = (unsigned)__shfl_xor((int)b, 32);
  unsigned r0 = hi ? bx : a;
  unsigned r1 = hi ? b : ax;
  a = r0; b = r1;
}
__device__ inline void plane_swap_f(float& a, float& b) {
  const bool hi = (threadIdx.x & 32) != 0;
  float ax = __shfl_xor(a, 32);
  float bx = __shfl_xor(b, 32);
  float r0 = hi ? bx : a;
  float r1 = hi ? b : ax;
  a = r0; b = r1;
}
#endif

// hi/lo double-bf16 split: a ~= hi + lo with ~16-bit effective mantissa
__device__ inline void split_bf(float a, ushort& hi, ushort& lo) {
  __hip_bfloat16 h = __float2bfloat16(a);
  float hf = __bfloat162float(h);
  __hip_bfloat16 l = __float2bfloat16(a - hf);
  union { __hip_bfloat16 b; ushort u; } c1, c2;
  c1.b = h; c2.b = l;
  hi = c1.u; lo = c2.u;
}

// ---------------- fused prep: cast X (blocks 0..8191), w=amp*cos(phase) hi/lo
// (blocks 8192..10239), cast basis q/k/v/o hi/lo (blocks 10240..10751)
__global__ __launch_bounds__(256) void prep(
    const float* __restrict__ X,
    const float* __restrict__ pq, const float* __restrict__ aq,
    const float* __restrict__ pk, const float* __restrict__ ak,
    const float* __restrict__ pv, const float* __restrict__ av,
    const float* __restrict__ po, const float* __restrict__ ao,
    const float* __restrict__ bq, const float* __restrict__ bk,
    const float* __restrict__ bv, const float* __restrict__ bo,
    ushort* __restrict__ Xh, ushort* __restrict__ Xl,
    ushort* __restrict__ Wh, ushort* __restrict__ Wl,
    ushort* __restrict__ Bh, ushort* __restrict__ Bl) {
  const int bid = blockIdx.x;
  const int t = threadIdx.x;
  if (bid < 8192) {
    size_t i = ((size_t)bid * 256 + t) * 4;
    float4 v = *(const float4*)&X[i];
    ushort4 h, l;
    split_bf(v.x, h.x, l.x); split_bf(v.y, h.y, l.y);
    split_bf(v.z, h.z, l.z); split_bf(v.w, h.w, l.w);
    *(ushort4*)&Xh[i] = h;
    *(ushort4*)&Xl[i] = l;
  } else if (bid < 10240) {
    int i = (bid - 8192) * 256 + t;
    const int N = HIDDEN * HARM;
    int set = i / N, j = i - set * N;
    const float* p = (set == 0) ? pq : (set == 1) ? pk : (set == 2) ? pv : po;
    const float* a = (set == 0) ? aq : (set == 1) ? ak : (set == 2) ? av : ao;
    float wv = a[j] * cosf(p[j]);
    ushort h, l;
    split_bf(wv, h, l);
    size_t o = (size_t)set * N + j;
    Wh[o] = h; Wl[o] = l;
  } else {
    int idx = bid - 10240;          // 512 blocks = 128 x 4
    int z = idx >> 7, xb = idx & 127;
    const float* S = (z == 0) ? bq : (z == 1) ? bk : (z == 2) ? bv : bo;
    size_t i = ((size_t)xb * 256 + t) * 4;
    float4 v = *(const float4*)&S[i];
    ushort4 h, l;
    split_bf(v.x, h.x, l.x); split_bf(v.y, h.y, l.y);
    split_bf(v.z, h.z, l.z); split_bf(v.w, h.w, l.w);
    size_t o = (size_t)z * HARM * HIDDEN + i;
    *(ushort4*)&Bh[o] = h;
    *(ushort4*)&Bl[o] = l;
  }
}

// --------------- MFMA resonance (double-bf16): Rp[kc][M][64] = X * basis^T
// 64-row tile / 36.8KB LDS / kc=4 — the verified-optimum geometry. Refuted
// alternatives: z-fusion (R11), pre-reduction kernel (R15), 128-row tile
// (R16, LDS->2/CU), kc=8 (R18, doubled partial-plane traffic).
__global__ __launch_bounds__(256) void gemm_res(
    const ushort* __restrict__ Xh, const ushort* __restrict__ Xl,
    const ushort* __restrict__ Bh, const ushort* __restrict__ Bl,
    float* __restrict__ R0, float* __restrict__ R1, float* __restrict__ R2) {
  const int z = blockIdx.z;
  const ushort* Bhz = Bh + (size_t)z * HARM * HIDDEN;
  const ushort* Blz = Bl + (size_t)z * HARM * HIDDEN;
  float* Rp = (z == 0) ? R0 : (z == 1) ? R1 : R2;
  const int row0 = blockIdx.x * 64;
  const int kc = blockIdx.y;
  __shared__ __align__(16) ushort Xs[2][64][72];
  __shared__ __align__(16) ushort Bs[2][64][72];
  const int t = threadIdx.x;
  const int lane = t & 63, w = t >> 6;
  const int l31 = lane & 31, hh = lane >> 5;
  const int m0 = (w & 1) * 32, n0 = (w >> 1) * 32;
  const int srow = t >> 2;
  const int sc = (t & 3) * 16;
  f32x16 acc;
  #pragma unroll
  for (int j = 0; j < 16; ++j) acc[j] = 0.0f;

  const int kbase = kc * 512;
  for (int k0 = kbase; k0 < kbase + 512; k0 += 64) {
    const size_t xo = (size_t)(row0 + srow) * HIDDEN + k0 + sc;
    const size_t bo = (size_t)srow * HIDDEN + k0 + sc;
    *(uint4*)&Xs[0][srow][sc]     = *(const uint4*)&Xh[xo];
    *(uint4*)&Xs[0][srow][sc + 8] = *(const uint4*)&Xh[xo + 8];
    *(uint4*)&Xs[1][srow][sc]     = *(const uint4*)&Xl[xo];
    *(uint4*)&Xs[1][srow][sc + 8] = *(const uint4*)&Xl[xo + 8];
    *(uint4*)&Bs[0][srow][sc]     = *(const uint4*)&Bhz[bo];
    *(uint4*)&Bs[0][srow][sc + 8] = *(const uint4*)&Bhz[bo + 8];
    *(uint4*)&Bs[1][srow][sc]     = *(const uint4*)&Blz[bo];
    *(uint4*)&Bs[1][srow][sc + 8] = *(const uint4*)&Blz[bo + 8];
    __syncthreads();
    #pragma unroll
    for (int ks = 0; ks < 4; ++ks) {
      bf16x8 ah = *(const bf16x8*)&Xs[0][m0 + l31][ks * 16 + 8 * hh];
      bf16x8 al = *(const bf16x8*)&Xs[1][m0 + l31][ks * 16 + 8 * hh];
      bf16x8 bh = *(const bf16x8*)&Bs[0][n0 + l31][ks * 16 + 8 * hh];
      bf16x8 bl = *(const bf16x8*)&Bs[1][n0 + l31][ks * 16 + 8 * hh];
      acc = __builtin_amdgcn_mfma_f32_32x32x16_bf16(ah, bh, acc, 0, 0, 0);
      acc = __builtin_amdgcn_mfma_f32_32x32x16_bf16(al, bh, acc, 0, 0, 0);
      acc = __builtin_amdgcn_mfma_f32_32x32x16_bf16(ah, bl, acc, 0, 0, 0);
    }
    __syncthreads();
  }
  float* out = Rp + (size_t)kc * ROWS * HARM;
  #pragma unroll
  for (int r = 0; r < 16; ++r) {
    int mloc = (r & 3) + 8 * (r >> 2) + 4 * hh;
    out[(size_t)(row0 + m0 + mloc) * HARM + n0 + l31] = acc[r];
  }
}

// --------------- MFMA projection (double-bf16): P = (sum_kc Rp) * W^T, bf16 out
// z=0 -> Qb, z=1 -> Kb, z=2 -> V written DIRECTLY TRANSPOSED into VtB via an LDS
// column tile. R-staging uses explicit float4 plane loads, left-assoc sum.
__global__ __launch_bounds__(256) void gemm_proj(
    const float* __restrict__ Rp0, const float* __restrict__ Rp1,
    const float* __restrict__ Rp2,
    const ushort* __restrict__ Wh, const ushort* __restrict__ Wl,
    ushort* __restrict__ P0, ushort* __restrict__ P1, ushort* __restrict__ Vt) {
  const int z = blockIdx.z;
  const float* Rp = (z == 0) ? Rp0 : (z == 1) ? Rp1 : Rp2;
  const ushort* Whz = Wh + (size_t)z * HIDDEN * HARM;
  const ushort* Wlz = Wl + (size_t)z * HIDDEN * HARM;
  const int row0 = blockIdx.x * 32;
  const int col0 = blockIdx.y * 128;
  __shared__ __align__(16) union PSM {
    struct { ushort Rs[2][32][72]; ushort Ws[2][128][72]; } s;
    ushort ct[128][36];   // [local col][local row] for the V-transpose epilogue
  } sm;
  const int t = threadIdx.x;
  const int lane = t & 63, w = t >> 6;
  const int l31 = lane & 31, hh = lane >> 5;
  {
    const int r = t >> 3, h0 = (t & 7) * 8;
    const size_t o = (size_t)(row0 + r) * HARM + h0;
    #pragma unroll
    for (int g = 0; g < 2; ++g) {
      const size_t o4 = o + g * 4;
      float4 p0 = *(const float4*)&Rp[o4];
      float4 p1 = *(const float4*)&Rp[RN + o4];
      float4 p2 = *(const float4*)&Rp[2 * (size_t)RN + o4];
      float4 p3 = *(const float4*)&Rp[3 * (size_t)RN + o4];
      float s0 = p0.x + p1.x + p2.x + p3.x;
      float s1 = p0.y + p1.y + p2.y + p3.y;
      float s2 = p0.z + p1.z + p2.z + p3.z;
      float s3 = p0.w + p1.w + p2.w + p3.w;
      ushort hi, lo;
      split_bf(s0, hi, lo);
      sm.s.Rs[0][r][h0 + g * 4 + 0] = hi; sm.s.Rs[1][r][h0 + g * 4 + 0] = lo;
      split_bf(s1, hi, lo);
      sm.s.Rs[0][r][h0 + g * 4 + 1] = hi; sm.s.Rs[1][r][h0 + g * 4 + 1] = lo;
      split_bf(s2, hi, lo);
      sm.s.Rs[0][r][h0 + g * 4 + 2] = hi; sm.s.Rs[1][r][h0 + g * 4 + 2] = lo;
      split_bf(s3, hi, lo);
      sm.s.Rs[0][r][h0 + g * 4 + 3] = hi; sm.s.Rs[1][r][h0 + g * 4 + 3] = lo;
    }
  }
  #pragma unroll
  for (int i = 0; i < 4; ++i) {
    int idx = t + i * 256;
    int o = idx >> 3, c8 = (idx & 7) * 8;
    const size_t go = (size_t)(col0 + o) * HARM + c8;
    *(uint4*)&sm.s.Ws[0][o][c8] = *(const uint4*)&Whz[go];
    *(uint4*)&sm.s.Ws[1][o][c8] = *(const uint4*)&Wlz[go];
  }
  __syncthreads();
  const int n0 = w * 32;
  f32x16 acc;
  #pragma unroll
  for (int j = 0; j < 16; ++j) acc[j] = 0.0f;
  #pragma unroll
  for (int ks = 0; ks < 4; ++ks) {
    bf16x8 ah = *(const bf16x8*)&sm.s.Rs[0][l31][ks * 16 + 8 * hh];
    bf16x8 al = *(const bf16x8*)&sm.s.Rs[1][l31][ks * 16 + 8 * hh];
    bf16x8 bh = *(const bf16x8*)&sm.s.Ws[0][n0 + l31][ks * 16 + 8 * hh];
    bf16x8 bl = *(const bf16x8*)&sm.s.Ws[1][n0 + l31][ks * 16 + 8 * hh];
    acc = __builtin_amdgcn_mfma_f32_32x32x16_bf16(ah, bh, acc, 0, 0, 0);
    acc = __builtin_amdgcn_mfma_f32_32x32x16_bf16(al, bh, acc, 0, 0, 0);
    acc = __builtin_amdgcn_mfma_f32_32x32x16_bf16(ah, bl, acc, 0, 0, 0);
  }
  if (z < 2) {
    ushort* P = (z == 0) ? P0 : P1;
    #pragma unroll
    for (int r = 0; r < 16; ++r) {
      int mloc = (r & 3) + 8 * (r >> 2) + 4 * hh;
      union { __hip_bfloat16 b; ushort u; } cv;
      cv.b = __float2bfloat16(acc[r]);
      P[(size_t)(row0 + mloc) * HIDDEN + col0 + n0 + l31] = cv.u;
    }
  } else {
    // V: route through LDS [col][row], store transposed with full 64B lines
    __syncthreads();   // staging reads finished everywhere before aliasing
    #pragma unroll
    for (int r = 0; r < 16; ++r) {
      int mloc = (r & 3) + 8 * (r >> 2) + 4 * hh;
      union { __hip_bfloat16 b; ushort u; } cv;
      cv.b = __float2bfloat16(acc[r]);
      sm.ct[n0 + l31][mloc] = cv.u;
    }
    __syncthreads();
    if (t < 128) {
      const int batch = row0 >> 11;
      const int tok0 = row0 & 2047;
      ushort* dst = Vt + (size_t)batch * SEQ * HIDDEN +
                    (size_t)(col0 + t) * SEQ + tok0;
      #pragma unroll
      for (int j = 0; j < 4; ++j)
        *(uint4*)&dst[j * 8] = *(const uint4*)&sm.ct[t][j * 8];
    }
  }
}

// --------------- MFMA final projection (double-bf16, fp32 out), grid (128, 16)
__global__ __launch_bounds__(256) void gemm_proj_f32(
    const float* __restrict__ Rp,
    const ushort* __restrict__ Whz, const ushort* __restrict__ Wlz,
    float* __restrict__ P) {
  const int row0 = blockIdx.x * 32;
  const int col0 = blockIdx.y * 128;
  __shared__ __align__(16) ushort Rs[2][32][72];
  __shared__ __align__(16) ushort Ws[2][128][72];
  const int t = threadIdx.x;
  const int lane = t & 63, w = t >> 6;
  const int l31 = lane & 31, hh = lane >> 5;
  {
    const int r = t >> 3, h0 = (t & 7) * 8;
    const size_t o = (size_t)(row0 + r) * HARM + h0;
    #pragma unroll
    for (int g = 0; g < 2; ++g) {
      const size_t o4 = o + g * 4;
      float4 p0 = *(const float4*)&Rp[o4];
      float4 p1 = *(const float4*)&Rp[RN + o4];
      float4 p2 = *(const float4*)&Rp[2 * (size_t)RN + o4];
      float4 p3 = *(const float4*)&Rp[3 * (size_t)RN + o4];
      float s0 = p0.x + p1.x + p2.x + p3.x;
      float s1 = p0.y + p1.y + p2.y + p3.y;
      float s2 = p0.z + p1.z + p2.z + p3.z;
      float s3 = p0.w + p1.w + p2.w + p3.w;
      ushort hi, lo;
      split_bf(s0, hi, lo);
      Rs[0][r][h0 + g * 4 + 0] = hi; Rs[1][r][h0 + g * 4 + 0] = lo;
      split_bf(s1, hi, lo);
      Rs[0][r][h0 + g * 4 + 1] = hi; Rs[1][r][h0 + g * 4 + 1] = lo;
      split_bf(s2, hi, lo);
      Rs[0][r][h0 + g * 4 + 2] = hi; Rs[1][r][h0 + g * 4 + 2] = lo;
      split_bf(s3, hi, lo);
      Rs[0][r][h0 + g * 4 + 3] = hi; Rs[1][r][h0 + g * 4 + 3] = lo;
    }
  }
  #pragma unroll
  for (int i = 0; i < 4; ++i) {
    int idx = t + i * 256;
    int o = idx >> 3, c8 = (idx & 7) * 8;
    const size_t go = (size_t)(col0 + o) * HARM + c8;
    *(uint4*)&Ws[0][o][c8] = *(const uint4*)&Whz[go];
    *(uint4*)&Ws[1][o][c8] = *(const uint4*)&Wlz[go];
  }
  __syncthreads();
  const int n0 = w * 32;
  f32x16 acc;
  #pragma unroll
  for (int j = 0; j < 16; ++j) acc[j] = 0.0f;
  #pragma unroll
  for (int ks = 0; ks < 4; ++ks) {
    bf16x8 ah = *(const bf16x8*)&Rs[0][l31][ks * 16 + 8 * hh];
    bf16x8 al = *(const bf16x8*)&Rs[1][l31][ks * 16 + 8 * hh];
    bf16x8 bh = *(const bf16x8*)&Ws[0][n0 + l31][ks * 16 + 8 * hh];
    bf16x8 bl = *(const bf16x8*)&Ws[1][n0 + l31][ks * 16 + 8 * hh];
    acc = __builtin_amdgcn_mfma_f32_32x32x16_bf16(ah, bh, acc, 0, 0, 0);
    acc = __builtin_amdgcn_mfma_f32_32x32x16_bf16(al, bh, acc, 0, 0, 0);
    acc = __builtin_amdgcn_mfma_f32_32x32x16_bf16(ah, bl, acc, 0, 0, 0);
  }
  #pragma unroll
  for (int r = 0; r < 16; ++r) {
    int mloc = (r & 3) + 8 * (r >> 2) + 4 * hh;
    P[(size_t)(row0 + mloc) * HIDDEN + col0 + n0 + l31] = acc[r];
  }
}

// ----------------------------------------------------------- MFMA flash attention
// R14 attn verbatim (best verified: ~102-106us, VGPR 88, no spill).
// Double-buffered kv[2] is load-bearing for register lifetime: single-buffer
// keeps kp/vp live across the whole body -> scratch spill (R12/R13).
#define BQ 128
#define BK 64
#define KSTR 136
#define VSTR 72

__device__ inline unsigned pkbf(float a, float b) {
  __hip_bfloat162 h2 = __float22bfloat162_rn(make_float2(a, b));
  union { __hip_bfloat162 h; unsigned u; } cv; cv.h = h2; return cv.u;
}

__global__ __launch_bounds__(256, 2) void attn_mfma(
    const ushort* __restrict__ Qg, const ushort* __restrict__ Kg,
    const ushort* __restrict__ Vt, ushort* __restrict__ Oh,
    ushort* __restrict__ Ol) {
  __shared__ __align__(16) union SM {
    ushort q[BQ][KSTR];
    struct { ushort k[BK][KSTR]; ushort v[HDIM][VSTR]; } kv[2];
  } sm;
  const int t = threadIdx.x;
  const int bh = blockIdx.x & 31;
  const int qt = blockIdx.x >> 5;
  const int b = bh >> 4, h = bh & 15;
  const int q0 = qt * BQ;
  const int lane = t & 63;
  const int w = t >> 6;
  const int l31 = lane & 31;
  const int hh = lane >> 5;
  const float SC2 = 0.08838834764831845f * 1.4426950408889634f;

  const int sk_key = t >> 4;
  const int sk_d0 = (t & 15) * 8;
  const int sv_d = t >> 3;
  const int sv_k = (t & 7) * 8;
  const size_t kbase = ((size_t)(b * SEQ)) * HIDDEN + h * HDIM;
  const size_t vbase = ((size_t)(b * SEQ + h * HDIM)) * SEQ;

  {
    const size_t gbase = ((size_t)(b * SEQ + q0)) * HIDDEN + h * HDIM;
    for (int p = 0; p < 8; ++p) {
      int row = p * 16 + sk_key;
      uint4 v = *(const uint4*)&Qg[gbase + (size_t)row * HIDDEN + sk_d0];
      *(uint4*)&sm.q[row][sk_d0] = v;
    }
  }
  __syncthreads();
  bf16x8 Qf[8];
  {
    const int qrow = w * 32 + l31;
    #pragma unroll
    for (int ks = 0; ks < 8; ++ks)
      Qf[ks] = *(const bf16x8*)&sm.q[qrow][ks * 16 + 8 * hh];
  }
  __syncthreads();

  float mrow = -1e30f, lsum = 0.0f;   // lsum: per-half partial, combined at end
  f32x16 Ot[4];
  #pragma unroll
  for (int i = 0; i < 4; ++i)
    #pragma unroll
    for (int j = 0; j < 16; ++j) Ot[i][j] = 0.0f;
  f32x16 Zv;
  #pragma unroll
  for (int j = 0; j < 16; ++j) Zv[j] = 0.0f;

  uint4 kp[4], vp[4];
  {
    const size_t gb = kbase;
    #pragma unroll
    for (int p = 0; p < 4; ++p)
      kp[p] = *(const uint4*)&Kg[gb + (size_t)(p * 16 + sk_key) * HIDDEN + sk_d0];
    #pragma unroll
    for (int p = 0; p < 4; ++p)
      vp[p] = *(const uint4*)&Vt[vbase + (size_t)(p * 32 + sv_d) * SEQ + sv_k];
    #pragma unroll
    for (int p = 0; p < 4; ++p)
      *(uint4*)&sm.kv[0].k[p * 16 + sk_key][sk_d0] = kp[p];
    #pragma unroll
    for (int p = 0; p < 4; ++p)
      *(uint4*)&sm.kv[0].v[p * 32 + sv_d][sv_k] = vp[p];
  }
  __syncthreads();

  for (int ci = 0; ci < 32; ++ci) {
    {
      const int cn = (ci < 31) ? ci + 1 : 31;
      const size_t gb = kbase + (size_t)(cn * BK) * HIDDEN;
      #pragma unroll
      for (int p = 0; p < 4; ++p)
        kp[p] = *(const uint4*)&Kg[gb + (size_t)(p * 16 + sk_key) * HIDDEN + sk_d0];
      const size_t vb = vbase + cn * BK;
      #pragma unroll
      for (int p = 0; p < 4; ++p)
        vp[p] = *(const uint4*)&Vt[vb + (size_t)(p * 32 + sv_d) * SEQ + sv_k];
    }
    const int cb = ci & 1;

    // ---- QK^T: first MFMA peeled onto a hoisted zero accumulator
    f32x16 C0, C1;
    {
      bf16x8 a0 = *(const bf16x8*)&sm.kv[cb].k[l31][8 * hh];
      bf16x8 a1 = *(const bf16x8*)&sm.kv[cb].k[32 + l31][8 * hh];
      __builtin_amdgcn_s_setprio(1);
      C0 = __builtin_amdgcn_mfma_f32_32x32x16_bf16(a0, Qf[0], Zv, 0, 0, 0);
      C1 = __builtin_amdgcn_mfma_f32_32x32x16_bf16(a1, Qf[0], Zv, 0, 0, 0);
      #pragma unroll
      for (int ks = 1; ks < 8; ++ks) {
        bf16x8 b0 = *(const bf16x8*)&sm.kv[cb].k[l31][ks * 16 + 8 * hh];
        bf16x8 b1 = *(const bf16x8*)&sm.kv[cb].k[32 + l31][ks * 16 + 8 * hh];
        C0 = __builtin_amdgcn_mfma_f32_32x32x16_bf16(b0, Qf[ks], C0, 0, 0, 0);
        C1 = __builtin_amdgcn_mfma_f32_32x32x16_bf16(b1, Qf[ks], C1, 0, 0, 0);
      }
      __builtin_amdgcn_s_setprio(0);
    }

    // ---- row max: ternary tree (fuses to v_max3), then orientation-safe
    // cross-half combine via permlane swap (max of {own, partner})
    float m01[16];
    #pragma unroll
    for (int j = 0; j < 16; ++j) m01[j] = fmaxf(C0[j], C1[j]);
    float x0 = fmaxf(fmaxf(m01[0], m01[1]), m01[2]);
    float x1 = fmaxf(fmaxf(m01[3], m01[4]), m01[5]);
    float x2 = fmaxf(fmaxf(m01[6], m01[7]), m01[8]);
    float x3 = fmaxf(fmaxf(m01[9], m01[10]), m01[11]);
    float x4 = fmaxf(fmaxf(m01[12], m01[13]), m01[14]);
    float mxr = fmaxf(fmaxf(fmaxf(x0, x1), fmaxf(x2, x3)), fmaxf(x4, m01[15]));
    {
      float u = mxr, v2 = mxr;
      plane_swap_f(u, v2);            // -> {lo-bcast, hi-bcast}: fmax = pair max
      mxr = fmaxf(u, v2);
    }

    // ---- exact online max: when no lane grows, every alpha would be exactly
    // 1.0, so skipping the rescale is bit-identical. Inside the branch each
    // lane keeps its own exact mnew (no stale shift -> P stays <= 1).
    const float mg = mxr * SC2;
    if (__any(mg > mrow)) {
      const float mnew = fmaxf(mrow, mg);
      const float alpha = EXP2F(mrow - mnew);   // exactly 1.0 where mg<=mrow
      lsum *= alpha;
      #pragma unroll
      for (int i = 0; i < 4; ++i)
        #pragma unroll
        for (int j = 0; j < 16; ++j) Ot[i][j] *= alpha;
      mrow = mnew;
    }
    float s0 = 0.0f, s1 = 0.0f, s2 = 0.0f, s3 = 0.0f;
    #pragma unroll
    for (int j = 0; j < 16; ++j) {
      float e0 = EXP2F(fmaf(C0[j], SC2, -mrow));
      float e1 = EXP2F(fmaf(C1[j], SC2, -mrow));
      C0[j] = e0; C1[j] = e1;
      if (j & 1) { s2 += e0; s3 += e1; } else { s0 += e0; s1 += e1; }
    }
    lsum += (s0 + s1) + (s2 + s3);   // per-half partial; combined in epilogue

    // ---- PV: packed pairs + permlane32_swap operand build (T12 recipe).
    #pragma unroll
    for (int st = 0; st < 4; ++st) {
      const int eb = 8 * (st & 1);
      unsigned A0, A1, B0, B1;
      if (st < 2) {
        A0 = pkbf(C0[eb + 0], C0[eb + 1]); A1 = pkbf(C0[eb + 2], C0[eb + 3]);
        B0 = pkbf(C0[eb + 4], C0[eb + 5]); B1 = pkbf(C0[eb + 6], C0[eb + 7]);
      } else {
        A0 = pkbf(C1[eb + 0], C1[eb + 1]); A1 = pkbf(C1[eb + 2], C1[eb + 3]);
        B0 = pkbf(C1[eb + 4], C1[eb + 5]); B1 = pkbf(C1[eb + 6], C1[eb + 7]);
      }
      plane_swap_u(A0, B0);
      plane_swap_u(A1, B1);
      union { unsigned u[4]; bf16x8 v; } cv;
      cv.u[0] = A0; cv.u[1] = A1; cv.u[2] = B0; cv.u[3] = B1;
      __builtin_amdgcn_s_setprio(1);
      #pragma unroll
      for (int mt = 0; mt < 4; ++mt) {
        bf16x8 a2 = *(const bf16x8*)&sm.kv[cb].v[mt * 32 + l31][st * 16 + 8 * hh];
        Ot[mt] = __builtin_amdgcn_mfma_f32_32x32x16_bf16(a2, cv.v, Ot[mt], 0, 0, 0);
      }
      __builtin_amdgcn_s_setprio(0);
    }

    {
      const int nb = cb ^ 1;
      #pragma unroll
      for (int p = 0; p < 4; ++p)
        *(uint4*)&sm.kv[nb].k[p * 16 + sk_key][sk_d0] = kp[p];
      #pragma unroll
      for (int p = 0; p < 4; ++p)
        *(uint4*)&sm.kv[nb].v[p * 32 + sv_d][sv_k] = vp[p];
    }
    __syncthreads();
  }

  // ---- epilogue: combine per-half lsum (orientation-safe swap-sum), then
  // normalized AO as bf16 hi/lo planes
  {
    float u = lsum, v2 = lsum;
    plane_swap_f(u, v2);
    lsum = u + v2;
  }
  const float inv = 1.0f / lsum;
  const int qrow = q0 + w * 32 + l31;
  const size_t ob = ((size_t)(b * SEQ + qrow)) * HIDDEN + h * HDIM;
  #pragma unroll
  for (int mt = 0; mt < 4; ++mt)
    #pragma unroll
    for (int g = 0; g < 4; ++g) {
      ushort4 hs, ls;
      split_bf(Ot[mt][4 * g + 0] * inv, hs.x, ls.x);
      split_bf(Ot[mt][4 * g + 1] * inv, hs.y, ls.y);
      split_bf(Ot[mt][4 * g + 2] * inv, hs.z, ls.z);
      split_bf(Ot[mt][4 * g + 3] * inv, hs.w, ls.w);
      const size_t off = ob + mt * 32 + 8 * g + 4 * hh;
      *(ushort4*)&Oh[off] = hs;
      *(ushort4*)&Ol[off] = ls;
    }
}

// -------------------------------------------------------------------------- launcher
extern "C" void kernel_launch(void* const* d_in, const int* in_sizes, int n_in,
                              void* d_out, int out_size, void* d_ws, size_t ws_size,
                              hipStream_t stream) {
  (void)in_sizes; (void)n_in; (void)out_size; (void)ws_size;
  const float* X       = (const float*)d_in[0];
  const float* basis_q = (const float*)d_in[1];
  const float* phase_q = (const float*)d_in[2];
  const float* amp_q   = (const float*)d_in[3];
  const float* basis_k = (const float*)d_in[4];
  const float* phase_k = (const float*)d_in[5];
  const float* amp_k   = (const float*)d_in[6];
  const float* basis_v = (const float*)d_in[7];
  const float* phase_v = (const float*)d_in[8];
  const float* amp_v   = (const float*)d_in[9];
  const float* basis_o = (const float*)d_in[10];
  const float* phase_o = (const float*)d_in[11];
  const float* amp_o   = (const float*)d_in[12];

  const size_t WN = (size_t)HIDDEN * HARM;   // 131072

  char* p = (char*)d_ws;
  ushort* Xhi = (ushort*)p; p += PN * 2;
  ushort* Xlo = (ushort*)p; p += PN * 2;
  ushort* Bhi = (ushort*)p; p += 4 * WN * 2;
  ushort* Blo = (ushort*)p; p += 4 * WN * 2;
  ushort* Whi = (ushort*)p; p += 4 * WN * 2;
  ushort* Wlo = (ushort*)p; p += 4 * WN * 2;
  float* Rqp = (float*)p; p += (size_t)4 * RN * 4;
  float* Rkp = (float*)p; p += (size_t)4 * RN * 4;
  float* Rvp = (float*)p; p += (size_t)4 * RN * 4;
  float* Rop = (float*)p; p += (size_t)4 * RN * 4;
  __hip_bfloat16* Qb = (__hip_bfloat16*)p; p += PN * 2;
  __hip_bfloat16* Kb = (__hip_bfloat16*)p; p += PN * 2;
  __hip_bfloat16* VtB = (__hip_bfloat16*)p; p += PN * 2;
  ushort* AOh = (ushort*)p; p += PN * 2;
  ushort* AOl = (ushort*)p; p += PN * 2;
  float* out = (float*)d_out;

  prep<<<10752, 256, 0, stream>>>(X,
                                  phase_q, amp_q, phase_k, amp_k,
                                  phase_v, amp_v, phase_o, amp_o,
                                  basis_q, basis_k, basis_v, basis_o,
                                  Xhi, Xlo, Whi, Wlo, Bhi, Blo);

  gemm_res<<<dim3(64, 4, 3), 256, 0, stream>>>(Xhi, Xlo, Bhi, Blo, Rqp, Rkp, Rvp);

  gemm_proj<<<dim3(128, 16, 3), 256, 0, stream>>>(
      Rqp, Rkp, Rvp, Whi, Wlo, (ushort*)Qb, (ushort*)Kb, (ushort*)VtB);

  attn_mfma<<<dim3((SEQ / BQ) * 32), 256, 0, stream>>>(
      (const ushort*)Qb, (const ushort*)Kb, (const ushort*)VtB, AOh, AOl);

  gemm_res<<<dim3(64, 4, 1), 256, 0, stream>>>(
      AOh, AOl, Bhi + 3 * WN, Blo + 3 * WN, Rop, Rop, Rop);

  gemm_proj_f32<<<dim3(128, 16), 256, 0, stream>>>(
      Rop, Whi + 3 * WN, Wlo + 3 * WN, out);
}